// Round 15
// baseline (108.187 us; speedup 1.0000x reference)
//
#include <hip/hip_runtime.h>
#include <hip/hip_bf16.h>
#include <hip/hip_fp16.h>

#define N_NODES 10000
#define N_EDGES 160000
#define FDIM    512
#define MPAD    10112   // 158 * 64
#define NGRAPH  64
#define OUTF    128
#define ELLW    64      // ELL width; P(deg>64) ~ 1e-15 for Poisson(16)
#define EBLK    625     // extract blocks: 625*256 = 160000
#define MAXPB   2564    // max prop2 blocks: sum_g ceil(sz_g/4) <= 2500+64

typedef __attribute__((ext_vector_type(8))) _Float16 f16x8;
typedef __attribute__((ext_vector_type(4))) float    f32x4;

__device__ __forceinline__ void gload_lds16(const void* g, void* l) {
    __builtin_amdgcn_global_load_lds(
        (const __attribute__((address_space(1))) void*)g,
        (__attribute__((address_space(3))) void*)l, 16, 0, 0);
}

// ---- W transpose + init roles: zero deg, goff binary search ----------------
__global__ __launch_bounds__(256) void prep_w(
    const float* __restrict__ W1, const float* __restrict__ W2,
    _Float16* __restrict__ W1T, _Float16* __restrict__ W2T,
    const unsigned* __restrict__ eraw, const unsigned* __restrict__ braw,
    int* __restrict__ deg_cnt, int* __restrict__ goff) {
    __shared__ float tile[64][65];
    __shared__ int s_is64;
    const float* W = blockIdx.z ? W2 : W1;
    _Float16*   T  = blockIdx.z ? W2T : W1T;
    int r0 = blockIdx.y * 64, c0 = blockIdx.x * 64;
    int t = threadIdx.x;
    int col = t & 63, rr = t >> 6;
    int flat = blockIdx.y * 8 + blockIdx.x;

    if (blockIdx.z == 0) {
        if (flat < 40) {                       // zero deg_cnt
            int id = flat * 256 + t;
            if (id < N_NODES) deg_cnt[id] = 0;
        } else if (flat == 41) {
            if (t < 64) {
                // edge_index in [0,10000): int64 -> all high words zero;
                // int32 -> odd words are random data (never all-zero).
                unsigned v = eraw[2 * t + 1];
                unsigned long long b = __ballot(v != 0u);
                if (t == 0) s_is64 = (b == 0ull) ? 1 : 0;
            }
            __syncthreads();
            if (t <= NGRAPH) {                 // batch sorted: binary search
                int is64 = s_is64;
                int lo = 0, hi = N_NODES;
                while (lo < hi) {
                    int mid = (lo + hi) >> 1;
                    int b = (int)(is64 ? braw[2 * mid] : braw[mid]);
                    if (b < t) lo = mid + 1; else hi = mid;
                }
                goff[t] = lo;
            }
        }
    }

    #pragma unroll
    for (int i = 0; i < 16; ++i) {
        int row = i * 4 + rr;
        tile[row][col] = W[(size_t)(r0 + row) * 512 + c0 + col];   // coalesced read
    }
    __syncthreads();
    #pragma unroll
    for (int i = 0; i < 16; ++i) {
        int orow = i * 4 + rr;                                     // output row = orig col
        T[(size_t)(c0 + orow) * 512 + r0 + col] = (_Float16)tile[col][orow]; // coalesced write
    }
}

// -------- pure GEMM: C = A @ B   (B as Bt[n][k]); norm lives in prop ---------
// AF32=1: A f32, converted during reg-staging. EXTRA>0: blocks >= NT build
// the ELL adjacency + pob (prop2 block offsets) — independent sibling work.
#define BM 64
#define BN 128
#define BK 64

template<int AF32, int EXTRA>
__global__ __launch_bounds__(256) void gemm_k(
    const void* __restrict__ Av, const _Float16* __restrict__ Bt,
    _Float16* __restrict__ C,
    const unsigned* __restrict__ eraw, int* __restrict__ deg_cnt,
    int* __restrict__ ell, const int* __restrict__ goff, int* __restrict__ pob) {
    __shared__ __align__(16) _Float16 Asm[BM * BK];
    __shared__ __align__(16) _Float16 Bsm[BN * BK];
    const int NT = (MPAD / BM) * (FDIM / BN);          // 632

    if (EXTRA && blockIdx.x >= NT) {                   // ---- ELL build blocks
        __shared__ int s_is64;
        __shared__ int s_goff[NGRAPH + 1];
        int t = threadIdx.x;
        if (t < 64) {
            unsigned v = eraw[2 * t + 1];
            unsigned long long b = __ballot(v != 0u);
            if (t == 0) s_is64 = (b == 0ull) ? 1 : 0;
        }
        if (blockIdx.x == NT && t <= NGRAPH) s_goff[t] = goff[t];
        __syncthreads();
        if (blockIdx.x == NT && t == 0) {              // pob: prop2 block offsets
            int run = 0;
            #pragma unroll 1
            for (int g = 0; g < NGRAPH; ++g) {
                pob[g] = run;
                run += (s_goff[g + 1] - s_goff[g] + 3) >> 2;
            }
            pob[NGRAPH] = run;
        }
        int e = (blockIdx.x - NT) * 256 + t;
        if (e >= N_EDGES) return;
        int is64 = s_is64;
        unsigned s, d;
        if (is64) { s = eraw[2 * e]; d = eraw[2 * (N_EDGES + e)]; }
        else      { s = eraw[e];     d = eraw[N_EDGES + e]; }
        int slot = atomicAdd(&deg_cnt[d], 1);
        if (slot < ELLW) ell[(size_t)d * ELLW + slot] = (int)s;
        return;
    }

    char* As = (char*)Asm;
    char* Bs = (char*)Bsm;
    const char* Ab = (const char*)Av;
    const char* Bb = (const char*)Bt;

    int tid  = threadIdx.x;
    int lane = tid & 63;
    int wave = tid >> 6;                    // 4 waves; wave w owns cols w*32..w*32+31

    int bid = blockIdx.x;
    int xcd = bid & 7, sub = bid >> 3;
    int q = NT >> 3, r = NT & 7;                       // 79, 0
    int base = (xcd < r) ? xcd * (q + 1) : r * (q + 1) + (xcd - r) * q;
    int tile = base + sub;
    int m0 = (tile >> 2) * BM;
    int n0 = (tile & 3) * BN;

    f32x4 acc[4][2] = {};

    for (int kt = 0; kt < FDIM; kt += BK) {
        if (AF32) {
            #pragma unroll
            for (int c = 0; c < 2; ++c) {
                int o   = (tid + c * 256) * 16;        // linear f16-tile byte offset
                int row = o >> 7;
                int cb  = o & 127;
                int gr  = m0 + row;
                f16x8 hv = (f16x8)0;
                if (gr < N_NODES) {
                    const float* sp = (const float*)(Ab + (size_t)gr * 2048 +
                                                     (size_t)kt * 4 + cb * 2);
                    float4 v0 = *(const float4*)sp;
                    float4 v1 = *(const float4*)(sp + 4);
                    hv[0] = (_Float16)v0.x; hv[1] = (_Float16)v0.y;
                    hv[2] = (_Float16)v0.z; hv[3] = (_Float16)v0.w;
                    hv[4] = (_Float16)v1.x; hv[5] = (_Float16)v1.y;
                    hv[6] = (_Float16)v1.z; hv[7] = (_Float16)v1.w;
                }
                *(f16x8*)(As + row * 128 + (cb ^ ((row & 7) << 4))) = hv;
            }
            #pragma unroll
            for (int i = 0; i < 4; ++i) {
                int o   = i * 4096 + wave * 1024 + lane * 16;
                int row = o >> 7;
                int cb  = o & 127;
                int scb = cb ^ ((row & 7) << 4);
                gload_lds16(Bb + (size_t)(n0 + row) * 1024 + kt * 2 + scb,
                            Bs + i * 4096 + wave * 1024);
            }
        } else {
            #pragma unroll
            for (int c = 0; c < 2; ++c) {          // A-tile: 8KB = 2 rounds
                int o   = c * 4096 + wave * 1024 + lane * 16;
                int row = o >> 7;
                int cb  = o & 127;
                int scb = cb ^ ((row & 7) << 4);
                gload_lds16(Ab + (size_t)(m0 + row) * 1024 + kt * 2 + scb,
                            As + c * 4096 + wave * 1024);
            }
            #pragma unroll
            for (int i = 0; i < 4; ++i) {          // B-tile: 16KB = 4 rounds
                int o   = i * 4096 + wave * 1024 + lane * 16;
                int row = o >> 7;
                int cb  = o & 127;
                int scb = cb ^ ((row & 7) << 4);
                gload_lds16(Bb + (size_t)(n0 + row) * 1024 + kt * 2 + scb,
                            Bs + i * 4096 + wave * 1024);
            }
        }
        __syncthreads();   // drains vmcnt + lgkmcnt before LDS reads

        #pragma unroll
        for (int kk = 0; kk < 2; ++kk) {
            f16x8 af[4], bf[2];
            int kb = kk * 64 + ((lane >> 4) << 4);        // byte offset in row
            #pragma unroll
            for (int fm = 0; fm < 4; ++fm) {              // rows 0..63 (broadcast)
                int rr = fm * 16 + (lane & 15);
                af[fm] = *(const f16x8*)(As + rr * 128 + (kb ^ ((rr & 7) << 4)));
            }
            #pragma unroll
            for (int fn = 0; fn < 2; ++fn) {              // cols wave*32 + fn*16
                int rr = wave * 32 + fn * 16 + (lane & 15);
                bf[fn] = *(const f16x8*)(Bs + rr * 128 + (kb ^ ((rr & 7) << 4)));
            }
            #pragma unroll
            for (int fm = 0; fm < 4; ++fm)
                #pragma unroll
                for (int fn = 0; fn < 2; ++fn)
                    acc[fm][fn] = __builtin_amdgcn_mfma_f32_16x16x32_f16(
                        af[fm], bf[fn], acc[fm][fn], 0, 0, 0);
        }
        __syncthreads();
    }

    #pragma unroll
    for (int fm = 0; fm < 4; ++fm) {
        #pragma unroll
        for (int r4 = 0; r4 < 4; ++r4) {
            int row = m0 + fm * 16 + ((lane >> 4) << 2) + r4;
            #pragma unroll
            for (int fn = 0; fn < 2; ++fn) {
                int cn = n0 + wave * 32 + fn * 16 + (lane & 15);
                C[(size_t)row * FDIM + cn] = (_Float16)acc[fm][fn][r4];
            }
        }
    }
}

// ---- shared gather body: na[8] = sum_s dinv_s*h[s] + dinv_d*h[d] ------------
__device__ __forceinline__ void gcn_gather(
    const char* base, const int* __restrict__ deg_cnt, const int* __restrict__ ell,
    int d, int lane, float dd, int deg, float (&acc)[8]) {
    f16x8 self = *(const f16x8*)(base + (size_t)d * 1024);
    #pragma unroll
    for (int i = 0; i < 8; ++i) acc[i] = dd * (float)self[i];
    int n = min(deg, ELLW);
    int sidx = 0; float wl = 0.0f;
    if (lane < n) {
        sidx = ell[(size_t)d * ELLW + lane];
        wl   = rsqrtf((float)(deg_cnt[sidx] + 1));
    }
    int k = 0;
    for (; k + 8 <= n; k += 8) {
        int s0 = __shfl(sidx, k + 0), s1 = __shfl(sidx, k + 1);
        int s2 = __shfl(sidx, k + 2), s3 = __shfl(sidx, k + 3);
        int s4 = __shfl(sidx, k + 4), s5 = __shfl(sidx, k + 5);
        int s6 = __shfl(sidx, k + 6), s7 = __shfl(sidx, k + 7);
        float w0 = __shfl(wl, k + 0), w1 = __shfl(wl, k + 1);
        float w2 = __shfl(wl, k + 2), w3 = __shfl(wl, k + 3);
        float w4 = __shfl(wl, k + 4), w5 = __shfl(wl, k + 5);
        float w6 = __shfl(wl, k + 6), w7 = __shfl(wl, k + 7);
        f16x8 v0 = *(const f16x8*)(base + (size_t)s0 * 1024);
        f16x8 v1 = *(const f16x8*)(base + (size_t)s1 * 1024);
        f16x8 v2 = *(const f16x8*)(base + (size_t)s2 * 1024);
        f16x8 v3 = *(const f16x8*)(base + (size_t)s3 * 1024);
        f16x8 v4 = *(const f16x8*)(base + (size_t)s4 * 1024);
        f16x8 v5 = *(const f16x8*)(base + (size_t)s5 * 1024);
        f16x8 v6 = *(const f16x8*)(base + (size_t)s6 * 1024);
        f16x8 v7 = *(const f16x8*)(base + (size_t)s7 * 1024);
        #pragma unroll
        for (int i = 0; i < 8; ++i)
            acc[i] += ((w0 * (float)v0[i] + w1 * (float)v1[i]) +
                       (w2 * (float)v2[i] + w3 * (float)v3[i])) +
                      ((w4 * (float)v4[i] + w5 * (float)v5[i]) +
                       (w6 * (float)v6[i] + w7 * (float)v7[i]));
    }
    if (k + 4 <= n) {
        int s0 = __shfl(sidx, k + 0), s1 = __shfl(sidx, k + 1);
        int s2 = __shfl(sidx, k + 2), s3 = __shfl(sidx, k + 3);
        float w0 = __shfl(wl, k + 0), w1 = __shfl(wl, k + 1);
        float w2 = __shfl(wl, k + 2), w3 = __shfl(wl, k + 3);
        f16x8 v0 = *(const f16x8*)(base + (size_t)s0 * 1024);
        f16x8 v1 = *(const f16x8*)(base + (size_t)s1 * 1024);
        f16x8 v2 = *(const f16x8*)(base + (size_t)s2 * 1024);
        f16x8 v3 = *(const f16x8*)(base + (size_t)s3 * 1024);
        #pragma unroll
        for (int i = 0; i < 8; ++i)
            acc[i] += (w0 * (float)v0[i] + w1 * (float)v1[i]) +
                      (w2 * (float)v2[i] + w3 * (float)v3[i]);
        k += 4;
    }
    for (; k < n; ++k) {
        int s = __shfl(sidx, k);
        float ws = __shfl(wl, k);
        f16x8 v = *(const f16x8*)(base + (size_t)s * 1024);
        #pragma unroll
        for (int i = 0; i < 8; ++i) acc[i] += ws * (float)v[i];
    }
}

// ---- prop layer 1: z[d] = relu(dd*(gather) + b), f16 out --------------------
__global__ __launch_bounds__(256) void prop_kernel(
    const _Float16* __restrict__ hs, const int* __restrict__ deg_cnt,
    const int* __restrict__ ell, const float* __restrict__ bias,
    _Float16* __restrict__ z) {
    int wid  = threadIdx.x >> 6;
    int lane = threadIdx.x & 63;
    int d = blockIdx.x * 4 + wid;                 // grid 2500 -> exactly 10000
    const char* base = (const char*)hs + lane * 16;
    int deg = deg_cnt[d];
    float dd = rsqrtf((float)(deg + 1));
    float acc[8];
    gcn_gather(base, deg_cnt, ell, d, lane, dd, deg, acc);
    float4 b0 = *(const float4*)(bias + lane * 8);
    float4 b1 = *(const float4*)(bias + lane * 8 + 4);
    f16x8 o;
    o[0] = (_Float16)fmaxf(acc[0] * dd + b0.x, 0.0f);
    o[1] = (_Float16)fmaxf(acc[1] * dd + b0.y, 0.0f);
    o[2] = (_Float16)fmaxf(acc[2] * dd + b0.z, 0.0f);
    o[3] = (_Float16)fmaxf(acc[3] * dd + b0.w, 0.0f);
    o[4] = (_Float16)fmaxf(acc[4] * dd + b1.x, 0.0f);
    o[5] = (_Float16)fmaxf(acc[5] * dd + b1.y, 0.0f);
    o[6] = (_Float16)fmaxf(acc[6] * dd + b1.z, 0.0f);
    o[7] = (_Float16)fmaxf(acc[7] * dd + b1.w, 0.0f);
    *(f16x8*)((char*)z + (size_t)d * 1024 + lane * 16) = o;
}

// ---- prop layer 2 FUSED with pooling. Graph-aligned blocks: block b handles
// <=4 nodes of ONE graph (pob prefix), LDS-reduces 4 relu rows, writes one
// f32 partial row. Full 2500-block TLP; no z2 buffer; no atomics.
__global__ __launch_bounds__(256) void prop_pool_kernel(
    const _Float16* __restrict__ hs, const int* __restrict__ deg_cnt,
    const int* __restrict__ ell, const float* __restrict__ bias,
    const int* __restrict__ goff, const int* __restrict__ pob,
    float* __restrict__ partials) {
    __shared__ int s_pob[NGRAPH + 1];
    __shared__ int s_goff[NGRAPH + 1];
    __shared__ float red[4][FDIM];
    int t = threadIdx.x;
    if (t <= NGRAPH) { s_pob[t] = pob[t]; s_goff[t] = goff[t]; }
    __syncthreads();
    int b = blockIdx.x;
    int wid = t >> 6, lane = t & 63;
    bool active = (b < s_pob[NGRAPH]);
    int g = 0, d = 0; bool valid = false;
    if (active) {
        int lo = 0, hi = NGRAPH - 1;                  // largest g: pob[g] <= b
        while (lo < hi) { int mid = (lo + hi + 1) >> 1;
                          if (s_pob[mid] <= b) lo = mid; else hi = mid - 1; }
        g = lo;
        d = s_goff[g] + (b - s_pob[g]) * 4 + wid;
        valid = (d < s_goff[g + 1]);
    }
    float acc[8] = {};
    if (valid) {
        const char* base = (const char*)hs + lane * 16;
        int deg = deg_cnt[d];
        float dd = rsqrtf((float)(deg + 1));
        gcn_gather(base, deg_cnt, ell, d, lane, dd, deg, acc);
        float4 b0 = *(const float4*)(bias + lane * 8);
        float4 b1 = *(const float4*)(bias + lane * 8 + 4);
        acc[0] = fmaxf(acc[0] * dd + b0.x, 0.0f);
        acc[1] = fmaxf(acc[1] * dd + b0.y, 0.0f);
        acc[2] = fmaxf(acc[2] * dd + b0.z, 0.0f);
        acc[3] = fmaxf(acc[3] * dd + b0.w, 0.0f);
        acc[4] = fmaxf(acc[4] * dd + b1.x, 0.0f);
        acc[5] = fmaxf(acc[5] * dd + b1.y, 0.0f);
        acc[6] = fmaxf(acc[6] * dd + b1.z, 0.0f);
        acc[7] = fmaxf(acc[7] * dd + b1.w, 0.0f);
    }
    #pragma unroll
    for (int i = 0; i < 8; ++i) red[wid][lane * 8 + i] = acc[i];
    __syncthreads();
    if (active) {
        float s1 = red[0][t]       + red[1][t]       + red[2][t]       + red[3][t];
        float s2 = red[0][t + 256] + red[1][t + 256] + red[2][t + 256] + red[3][t + 256];
        partials[(size_t)b * FDIM + t]       = s1;
        partials[(size_t)b * FDIM + t + 256] = s2;
    }
}

// ---- final: reduce graph's partial rows -> pooled (d_out) -> matmul ---------
__global__ void final_kernel(const float* __restrict__ partials, const int* __restrict__ pob,
                             const float* __restrict__ Wlin, const float* __restrict__ blin,
                             float* __restrict__ pooled_out, float* __restrict__ out) {
    __shared__ float p[FDIM];
    int g = blockIdx.x, t = threadIdx.x;          // 128 threads: one feature-quad each
    int wb = pob[g], we = pob[g + 1];
    f32x4 acc4 = {};
    for (int b = wb; b < we; ++b)
        acc4 += *(const f32x4*)(partials + (size_t)b * FDIM + t * 4);
    *(f32x4*)(p + t * 4) = acc4;
    *(f32x4*)(pooled_out + (size_t)g * FDIM + t * 4) = acc4;
    __syncthreads();
    float acc = blin[t];
    for (int k = 0; k < FDIM; ++k) acc += p[k] * Wlin[k * OUTF + t];
    out[g * OUTF + t] = acc;
}

// ---------------- launch -----------------------------------------------------
extern "C" void kernel_launch(void* const* d_in, const int* in_sizes, int n_in,
                              void* d_out, int out_size, void* d_ws, size_t ws_size,
                              hipStream_t stream) {
    const float*    x    = (const float*)d_in[0];
    const float*    W1   = (const float*)d_in[1];
    const float*    b1   = (const float*)d_in[2];
    const float*    W2   = (const float*)d_in[3];
    const float*    b2   = (const float*)d_in[4];
    const float*    Wlin = (const float*)d_in[5];
    const float*    blin = (const float*)d_in[6];
    const unsigned* eidx = (const unsigned*)d_in[7];
    const unsigned* bat  = (const unsigned*)d_in[8];
    float* out = (float*)d_out;

    char* w = (char*)d_ws;
    auto alloc = [&](size_t sz) { char* p = w; w += (sz + 255) & ~255ull; return p; };
    _Float16* buf0 = (_Float16*)alloc((size_t)MPAD * FDIM * 2);  // h1
    _Float16* buf1 = (_Float16*)alloc((size_t)MPAD * FDIM * 2);  // z1
    _Float16* buf2 = (_Float16*)alloc((size_t)MPAD * FDIM * 2);  // h2
    _Float16* W1T  = (_Float16*)alloc(512 * 512 * 2);
    _Float16* W2T  = (_Float16*)alloc(512 * 512 * 2);
    float* partials= (float*)alloc((size_t)MAXPB * FDIM * 4);
    int*   ell     = (int*)alloc((size_t)N_NODES * ELLW * 4);
    int*   deg_cnt = (int*)alloc(MPAD * 4);
    int*   goff    = (int*)alloc((NGRAPH + 1) * 4);
    int*   pob     = (int*)alloc((NGRAPH + 1) * 4);

    const int NT = (MPAD / BM) * (FDIM / BN);                   // 632

    // 1: W transpose + init (zero deg, goff)
    prep_w<<<dim3(8, 8, 2), 256, 0, stream>>>(W1, W2, W1T, W2T, eidx, bat, deg_cnt, goff);
    // 2: gemm1 (pure) + ELL build + pob in extra blocks of the same launch
    gemm_k<1, 1><<<NT + EBLK, 256, 0, stream>>>(x, W1T, buf0, eidx, deg_cnt, ell, goff, pob);
    // 3-5: prop1 -> gemm2 -> fused prop2+pool
    prop_kernel<<<N_NODES / 4, 256, 0, stream>>>(buf0, deg_cnt, ell, b1, buf1); // z1
    gemm_k<0, 0><<<NT, 256, 0, stream>>>(buf1, W2T, buf2, nullptr, nullptr, nullptr,
                                         nullptr, nullptr);
    prop_pool_kernel<<<MAXPB, 256, 0, stream>>>(buf2, deg_cnt, ell, b2, goff, pob, partials);
    // 6: reduce partial rows + final linear
    final_kernel<<<NGRAPH, 128, 0, stream>>>(partials, pob, Wlin, blin,
                                             out, out + NGRAPH * FDIM);
}

// Round 16
// 105.349 us; speedup vs baseline: 1.0269x; 1.0269x over previous
//
#include <hip/hip_runtime.h>
#include <hip/hip_bf16.h>
#include <hip/hip_fp16.h>

#define N_NODES 10000
#define N_EDGES 160000
#define FDIM    512
#define MPAD    10112   // 158 * 64
#define NGRAPH  64
#define OUTF    128
#define PCHUNK  32      // pooling chunks per graph
#define ELLW    64      // ELL width; P(deg>64) ~ 1e-15 for Poisson(16)
#define EBLK    625     // extract blocks: 625*256 = 160000
#define TBLK    64      // W2-transpose blocks (8x8 tiles of 64x64)

typedef __attribute__((ext_vector_type(8))) _Float16 f16x8;
typedef __attribute__((ext_vector_type(4))) float    f32x4;

__device__ __forceinline__ void gload_lds16(const void* g, void* l) {
    __builtin_amdgcn_global_load_lds(
        (const __attribute__((address_space(1))) void*)g,
        (__attribute__((address_space(3))) void*)l, 16, 0, 0);
}

// ---- W1 transpose + init roles: zero deg, goff binary search ----------------
__global__ __launch_bounds__(256) void prep_w(
    const float* __restrict__ W1, _Float16* __restrict__ W1T,
    const unsigned* __restrict__ eraw, const unsigned* __restrict__ braw,
    int* __restrict__ deg_cnt, int* __restrict__ goff) {
    __shared__ float tile[64][65];
    __shared__ int s_is64;
    int r0 = blockIdx.y * 64, c0 = blockIdx.x * 64;
    int t = threadIdx.x;
    int col = t & 63, rr = t >> 6;
    int flat = blockIdx.y * 8 + blockIdx.x;

    if (flat < 40) {                       // zero deg_cnt
        int id = flat * 256 + t;
        if (id < N_NODES) deg_cnt[id] = 0;
    } else if (flat == 41) {
        if (t < 64) {
            // edge_index in [0,10000): int64 -> all high words zero;
            // int32 -> odd words are random data (never all-zero).
            unsigned v = eraw[2 * t + 1];
            unsigned long long b = __ballot(v != 0u);
            if (t == 0) s_is64 = (b == 0ull) ? 1 : 0;
        }
        __syncthreads();
        if (t <= NGRAPH) {                 // batch sorted: binary search
            int is64 = s_is64;
            int lo = 0, hi = N_NODES;
            while (lo < hi) {
                int mid = (lo + hi) >> 1;
                int b = (int)(is64 ? braw[2 * mid] : braw[mid]);
                if (b < t) lo = mid + 1; else hi = mid;
            }
            goff[t] = lo;
        }
    }

    #pragma unroll
    for (int i = 0; i < 16; ++i) {
        int row = i * 4 + rr;
        tile[row][col] = W1[(size_t)(r0 + row) * 512 + c0 + col];  // coalesced read
    }
    __syncthreads();
    #pragma unroll
    for (int i = 0; i < 16; ++i) {
        int orow = i * 4 + rr;                                     // output row = orig col
        W1T[(size_t)(c0 + orow) * 512 + r0 + col] = (_Float16)tile[col][orow];
    }
}

// -------- pure GEMM: C = A @ B   (B as Bt[n][k]); norm lives in prop ---------
// AF32=1: A f32, converted during reg-staging. EXTRA>0: sibling blocks build
// the ELL adjacency (blocks NT..NT+EBLK) and transpose W2 (last TBLK blocks).
#define BM 64
#define BN 128
#define BK 64

template<int AF32, int EXTRA>
__global__ __launch_bounds__(256) void gemm_k(
    const void* __restrict__ Av, const _Float16* __restrict__ Bt,
    _Float16* __restrict__ C,
    const unsigned* __restrict__ eraw, int* __restrict__ deg_cnt,
    int* __restrict__ ell, const float* __restrict__ W2, _Float16* __restrict__ W2T) {
    __shared__ __align__(16) char smem[BM * BK * 2 + BN * BK * 2];  // 24KB arena
    __shared__ int s_is64;
    const int NT = (MPAD / BM) * (FDIM / BN);          // 632

    if (EXTRA && blockIdx.x >= NT + EBLK) {            // ---- W2 transpose blocks
        float (*tile)[65] = (float(*)[65])smem;        // 16.6KB <= 24KB arena
        int tb = blockIdx.x - NT - EBLK;
        int r0 = (tb >> 3) * 64, c0 = (tb & 7) * 64;
        int t = threadIdx.x;
        int col = t & 63, rr = t >> 6;
        #pragma unroll
        for (int i = 0; i < 16; ++i) {
            int row = i * 4 + rr;
            tile[row][col] = W2[(size_t)(r0 + row) * 512 + c0 + col];
        }
        __syncthreads();
        #pragma unroll
        for (int i = 0; i < 16; ++i) {
            int orow = i * 4 + rr;
            W2T[(size_t)(c0 + orow) * 512 + r0 + col] = (_Float16)tile[col][orow];
        }
        return;
    }

    if (EXTRA && blockIdx.x >= NT) {                   // ---- ELL build blocks
        int t = threadIdx.x;
        if (t < 64) {
            unsigned v = eraw[2 * t + 1];
            unsigned long long b = __ballot(v != 0u);
            if (t == 0) s_is64 = (b == 0ull) ? 1 : 0;
        }
        __syncthreads();
        int e = (blockIdx.x - NT) * 256 + t;
        if (e >= N_EDGES) return;
        int is64 = s_is64;
        unsigned s, d;
        if (is64) { s = eraw[2 * e]; d = eraw[2 * (N_EDGES + e)]; }
        else      { s = eraw[e];     d = eraw[N_EDGES + e]; }
        int slot = atomicAdd(&deg_cnt[d], 1);
        if (slot < ELLW) ell[(size_t)d * ELLW + slot] = (int)s;
        return;
    }

    char* As = smem;                  // 8KB
    char* Bs = smem + BM * BK * 2;    // 16KB
    const char* Ab = (const char*)Av;
    const char* Bb = (const char*)Bt;

    int tid  = threadIdx.x;
    int lane = tid & 63;
    int wave = tid >> 6;                    // 4 waves; wave w owns cols w*32..w*32+31

    int bid = blockIdx.x;
    int xcd = bid & 7, sub = bid >> 3;
    int q = NT >> 3, r = NT & 7;                       // 79, 0
    int base = (xcd < r) ? xcd * (q + 1) : r * (q + 1) + (xcd - r) * q;
    int tile = base + sub;
    int m0 = (tile >> 2) * BM;
    int n0 = (tile & 3) * BN;

    f32x4 acc[4][2] = {};

    for (int kt = 0; kt < FDIM; kt += BK) {
        if (AF32) {
            #pragma unroll
            for (int c = 0; c < 2; ++c) {
                int o   = (tid + c * 256) * 16;        // linear f16-tile byte offset
                int row = o >> 7;
                int cb  = o & 127;
                int gr  = m0 + row;
                f16x8 hv = (f16x8)0;
                if (gr < N_NODES) {
                    const float* sp = (const float*)(Ab + (size_t)gr * 2048 +
                                                     (size_t)kt * 4 + cb * 2);
                    float4 v0 = *(const float4*)sp;
                    float4 v1 = *(const float4*)(sp + 4);
                    hv[0] = (_Float16)v0.x; hv[1] = (_Float16)v0.y;
                    hv[2] = (_Float16)v0.z; hv[3] = (_Float16)v0.w;
                    hv[4] = (_Float16)v1.x; hv[5] = (_Float16)v1.y;
                    hv[6] = (_Float16)v1.z; hv[7] = (_Float16)v1.w;
                }
                *(f16x8*)(As + row * 128 + (cb ^ ((row & 7) << 4))) = hv;
            }
            #pragma unroll
            for (int i = 0; i < 4; ++i) {
                int o   = i * 4096 + wave * 1024 + lane * 16;
                int row = o >> 7;
                int cb  = o & 127;
                int scb = cb ^ ((row & 7) << 4);
                gload_lds16(Bb + (size_t)(n0 + row) * 1024 + kt * 2 + scb,
                            Bs + i * 4096 + wave * 1024);
            }
        } else {
            #pragma unroll
            for (int c = 0; c < 2; ++c) {          // A-tile: 8KB = 2 rounds
                int o   = c * 4096 + wave * 1024 + lane * 16;
                int row = o >> 7;
                int cb  = o & 127;
                int scb = cb ^ ((row & 7) << 4);
                gload_lds16(Ab + (size_t)(m0 + row) * 1024 + kt * 2 + scb,
                            As + c * 4096 + wave * 1024);
            }
            #pragma unroll
            for (int i = 0; i < 4; ++i) {          // B-tile: 16KB = 4 rounds
                int o   = i * 4096 + wave * 1024 + lane * 16;
                int row = o >> 7;
                int cb  = o & 127;
                int scb = cb ^ ((row & 7) << 4);
                gload_lds16(Bb + (size_t)(n0 + row) * 1024 + kt * 2 + scb,
                            Bs + i * 4096 + wave * 1024);
            }
        }
        __syncthreads();   // drains vmcnt + lgkmcnt before LDS reads

        #pragma unroll
        for (int kk = 0; kk < 2; ++kk) {
            f16x8 af[4], bf[2];
            int kb = kk * 64 + ((lane >> 4) << 4);        // byte offset in row
            #pragma unroll
            for (int fm = 0; fm < 4; ++fm) {              // rows 0..63 (broadcast)
                int rr = fm * 16 + (lane & 15);
                af[fm] = *(const f16x8*)(As + rr * 128 + (kb ^ ((rr & 7) << 4)));
            }
            #pragma unroll
            for (int fn = 0; fn < 2; ++fn) {              // cols wave*32 + fn*16
                int rr = wave * 32 + fn * 16 + (lane & 15);
                bf[fn] = *(const f16x8*)(Bs + rr * 128 + (kb ^ ((rr & 7) << 4)));
            }
            #pragma unroll
            for (int fm = 0; fm < 4; ++fm)
                #pragma unroll
                for (int fn = 0; fn < 2; ++fn)
                    acc[fm][fn] = __builtin_amdgcn_mfma_f32_16x16x32_f16(
                        af[fm], bf[fn], acc[fm][fn], 0, 0, 0);
        }
        __syncthreads();
    }

    #pragma unroll
    for (int fm = 0; fm < 4; ++fm) {
        #pragma unroll
        for (int r4 = 0; r4 < 4; ++r4) {
            int row = m0 + fm * 16 + ((lane >> 4) << 2) + r4;
            #pragma unroll
            for (int fn = 0; fn < 2; ++fn) {
                int cn = n0 + wave * 32 + fn * 16 + (lane & 15);
                C[(size_t)row * FDIM + cn] = (_Float16)acc[fm][fn][r4];
            }
        }
    }
}

// ---- propagation (full GCN norm here):
// z[d] = relu( dinv_d * ( sum_s dinv_s*h[s] + dinv_d*h[d] ) + b ),  dinv=rsqrt(deg+1)
__global__ __launch_bounds__(256) void prop_kernel(
    const _Float16* __restrict__ hs, const int* __restrict__ deg_cnt,
    const int* __restrict__ ell, const float* __restrict__ bias,
    _Float16* __restrict__ z) {
    int wid  = threadIdx.x >> 6;
    int lane = threadIdx.x & 63;
    int d = blockIdx.x * 4 + wid;                 // grid 2500 -> exactly 10000
    const char* base = (const char*)hs + lane * 16;
    int deg = deg_cnt[d];
    float dd = rsqrtf((float)(deg + 1));
    f16x8 self = *(const f16x8*)(base + (size_t)d * 1024);
    float acc[8];
    #pragma unroll
    for (int i = 0; i < 8; ++i) acc[i] = dd * (float)self[i];
    int n = min(deg, ELLW);
    int sidx = 0; float wl = 0.0f;
    if (lane < n) {
        sidx = ell[(size_t)d * ELLW + lane];
        wl   = rsqrtf((float)(deg_cnt[sidx] + 1));
    }
    int k = 0;
    for (; k + 8 <= n; k += 8) {
        int s0 = __shfl(sidx, k + 0), s1 = __shfl(sidx, k + 1);
        int s2 = __shfl(sidx, k + 2), s3 = __shfl(sidx, k + 3);
        int s4 = __shfl(sidx, k + 4), s5 = __shfl(sidx, k + 5);
        int s6 = __shfl(sidx, k + 6), s7 = __shfl(sidx, k + 7);
        float w0 = __shfl(wl, k + 0), w1 = __shfl(wl, k + 1);
        float w2 = __shfl(wl, k + 2), w3 = __shfl(wl, k + 3);
        float w4 = __shfl(wl, k + 4), w5 = __shfl(wl, k + 5);
        float w6 = __shfl(wl, k + 6), w7 = __shfl(wl, k + 7);
        f16x8 v0 = *(const f16x8*)(base + (size_t)s0 * 1024);
        f16x8 v1 = *(const f16x8*)(base + (size_t)s1 * 1024);
        f16x8 v2 = *(const f16x8*)(base + (size_t)s2 * 1024);
        f16x8 v3 = *(const f16x8*)(base + (size_t)s3 * 1024);
        f16x8 v4 = *(const f16x8*)(base + (size_t)s4 * 1024);
        f16x8 v5 = *(const f16x8*)(base + (size_t)s5 * 1024);
        f16x8 v6 = *(const f16x8*)(base + (size_t)s6 * 1024);
        f16x8 v7 = *(const f16x8*)(base + (size_t)s7 * 1024);
        #pragma unroll
        for (int i = 0; i < 8; ++i)
            acc[i] += ((w0 * (float)v0[i] + w1 * (float)v1[i]) +
                       (w2 * (float)v2[i] + w3 * (float)v3[i])) +
                      ((w4 * (float)v4[i] + w5 * (float)v5[i]) +
                       (w6 * (float)v6[i] + w7 * (float)v7[i]));
    }
    if (k + 4 <= n) {
        int s0 = __shfl(sidx, k + 0), s1 = __shfl(sidx, k + 1);
        int s2 = __shfl(sidx, k + 2), s3 = __shfl(sidx, k + 3);
        float w0 = __shfl(wl, k + 0), w1 = __shfl(wl, k + 1);
        float w2 = __shfl(wl, k + 2), w3 = __shfl(wl, k + 3);
        f16x8 v0 = *(const f16x8*)(base + (size_t)s0 * 1024);
        f16x8 v1 = *(const f16x8*)(base + (size_t)s1 * 1024);
        f16x8 v2 = *(const f16x8*)(base + (size_t)s2 * 1024);
        f16x8 v3 = *(const f16x8*)(base + (size_t)s3 * 1024);
        #pragma unroll
        for (int i = 0; i < 8; ++i)
            acc[i] += (w0 * (float)v0[i] + w1 * (float)v1[i]) +
                      (w2 * (float)v2[i] + w3 * (float)v3[i]);
        k += 4;
    }
    for (; k < n; ++k) {
        int s = __shfl(sidx, k);
        float ws = __shfl(wl, k);
        f16x8 v = *(const f16x8*)(base + (size_t)s * 1024);
        #pragma unroll
        for (int i = 0; i < 8; ++i) acc[i] += ws * (float)v[i];
    }
    float4 b0 = *(const float4*)(bias + lane * 8);
    float4 b1 = *(const float4*)(bias + lane * 8 + 4);
    f16x8 o;
    o[0] = (_Float16)fmaxf(acc[0] * dd + b0.x, 0.0f);
    o[1] = (_Float16)fmaxf(acc[1] * dd + b0.y, 0.0f);
    o[2] = (_Float16)fmaxf(acc[2] * dd + b0.z, 0.0f);
    o[3] = (_Float16)fmaxf(acc[3] * dd + b0.w, 0.0f);
    o[4] = (_Float16)fmaxf(acc[4] * dd + b1.x, 0.0f);
    o[5] = (_Float16)fmaxf(acc[5] * dd + b1.y, 0.0f);
    o[6] = (_Float16)fmaxf(acc[6] * dd + b1.z, 0.0f);
    o[7] = (_Float16)fmaxf(acc[7] * dd + b1.w, 0.0f);
    *(f16x8*)((char*)z + (size_t)d * 1024 + lane * 16) = o;
}

// ---- pooling stage 1: per-(graph,chunk) partial sums, no atomics ------------
__global__ __launch_bounds__(64) void pool_kernel(
    const _Float16* __restrict__ z, const int* __restrict__ goff,
    float* __restrict__ partials) {
    int g = blockIdx.x, c = blockIdx.y;           // grid (64, PCHUNK)
    int lane = threadIdx.x;
    float acc[8] = {};
    int e = goff[g + 1];
    for (int n = goff[g] + c; n < e; n += PCHUNK) {
        f16x8 v = *(const f16x8*)((const char*)z + (size_t)n * 1024 + lane * 16);
        #pragma unroll
        for (int i = 0; i < 8; ++i) acc[i] += (float)v[i];
    }
    float* p = partials + ((size_t)c * NGRAPH + g) * FDIM + lane * 8;
    #pragma unroll
    for (int i = 0; i < 8; ++i) p[i] = acc[i];
}

// ---- final: parallel chunk reduce -> pooled (d_out) -> matmul (d_out) -------
__global__ void final_kernel(const float* __restrict__ partials, const float* __restrict__ Wlin,
                             const float* __restrict__ blin, float* __restrict__ pooled_out,
                             float* __restrict__ out) {
    __shared__ float p[FDIM];
    int g = blockIdx.x, t = threadIdx.x;          // 128 threads: one feature-quad each
    f32x4 acc4 = {};
    #pragma unroll
    for (int c = 0; c < PCHUNK; ++c) {
        f32x4 v = *(const f32x4*)(partials + ((size_t)c * NGRAPH + g) * FDIM + t * 4);
        acc4 += v;
    }
    *(f32x4*)(p + t * 4) = acc4;
    *(f32x4*)(pooled_out + (size_t)g * FDIM + t * 4) = acc4;
    __syncthreads();
    float acc = blin[t];
    for (int k = 0; k < FDIM; ++k) acc += p[k] * Wlin[k * OUTF + t];
    out[g * OUTF + t] = acc;
}

// ---------------- launch -----------------------------------------------------
extern "C" void kernel_launch(void* const* d_in, const int* in_sizes, int n_in,
                              void* d_out, int out_size, void* d_ws, size_t ws_size,
                              hipStream_t stream) {
    const float*    x    = (const float*)d_in[0];
    const float*    W1   = (const float*)d_in[1];
    const float*    b1   = (const float*)d_in[2];
    const float*    W2   = (const float*)d_in[3];
    const float*    b2   = (const float*)d_in[4];
    const float*    Wlin = (const float*)d_in[5];
    const float*    blin = (const float*)d_in[6];
    const unsigned* eidx = (const unsigned*)d_in[7];
    const unsigned* bat  = (const unsigned*)d_in[8];
    float* out = (float*)d_out;

    char* w = (char*)d_ws;
    auto alloc = [&](size_t sz) { char* p = w; w += (sz + 255) & ~255ull; return p; };
    _Float16* buf0 = (_Float16*)alloc((size_t)MPAD * FDIM * 2);  // h1
    _Float16* buf1 = (_Float16*)alloc((size_t)MPAD * FDIM * 2);  // z1, then z2
    _Float16* buf2 = (_Float16*)alloc((size_t)MPAD * FDIM * 2);  // h2
    _Float16* W1T  = (_Float16*)alloc(512 * 512 * 2);
    _Float16* W2T  = (_Float16*)alloc(512 * 512 * 2);
    float* partials= (float*)alloc((size_t)PCHUNK * NGRAPH * FDIM * 4);
    int*   ell     = (int*)alloc((size_t)N_NODES * ELLW * 4);
    int*   deg_cnt = (int*)alloc(MPAD * 4);
    int*   goff    = (int*)alloc((NGRAPH + 1) * 4);

    const int NT = (MPAD / BM) * (FDIM / BN);                   // 632

    // 1: W1 transpose + init (zero deg, goff)
    prep_w<<<dim3(8, 8), 256, 0, stream>>>(W1, W1T, eidx, bat, deg_cnt, goff);
    // 2: gemm1 (pure) + ELL build + W2 transpose as sibling blocks
    gemm_k<1, 1><<<NT + EBLK + TBLK, 256, 0, stream>>>(x, W1T, buf0,
                                                       eidx, deg_cnt, ell, W2, W2T);
    // 3-5: prop1 -> gemm2 -> prop2
    prop_kernel<<<N_NODES / 4, 256, 0, stream>>>(buf0, deg_cnt, ell, b1, buf1); // z1
    gemm_k<0, 0><<<NT, 256, 0, stream>>>(buf1, W2T, buf2, nullptr, nullptr, nullptr,
                                         nullptr, nullptr);
    prop_kernel<<<N_NODES / 4, 256, 0, stream>>>(buf2, deg_cnt, ell, b2, buf1); // z2
    // 6-7: pool partials -> fused reduce+final
    pool_kernel<<<dim3(NGRAPH, PCHUNK), 64, 0, stream>>>(buf1, goff, partials);
    final_kernel<<<NGRAPH, 128, 0, stream>>>(partials, Wlin, blin, out, out + NGRAPH * FDIM);
}